// Round 7
// baseline (475.867 us; speedup 1.0000x reference)
//
#include <hip/hip_runtime.h>
#include <stdint.h>

// Problem constants (from reference)
#define NNODES 50000
#define NEDGES 1000000
#define DIM    64
#define NREL   8
#define NBUCK  391          // ceil(50000/128); bucket = dst >> 7 (128-node range)
#define BCAP   2944         // per-bucket staging capacity (expected ~2558, +7.6 sigma)
#define KEYS   1024         // 128 nodes x 8 rels per bucket
#define NBLK   3125         // 50000 / 16 output blocks
#define PITCHF 577          // LDS accum row pitch in floats (577 mod 32 == 1: conflict-free)

typedef __attribute__((ext_vector_type(8))) short short8;
typedef __attribute__((ext_vector_type(4))) float float4v;
typedef __attribute__((ext_vector_type(4))) unsigned short us4;

__device__ __forceinline__ float bf2f(unsigned short u) {
  return __uint_as_float(((unsigned int)u) << 16);
}
__device__ __forceinline__ unsigned short f2bf(float f) {
  unsigned int u = __float_as_uint(f);
  unsigned int r = (u + 0x7FFF + ((u >> 16) & 1)) >> 16;   // round-nearest-even
  return (unsigned short)r;
}

#define CASTBLK ((NNODES * DIM / 4 + 255) / 256)
#define PREPBLK ((18 * 4 * 64 * 8 + 255) / 256)

// K0: fused prep (B fragments + bias) and x f32->bf16 cast; zero bucket_cursor.
// Bf2[((ks*4+ct)*64 + l)*8 + j] = Bmat[ks*32 + (l>>4)*8 + j][ct*16 + (l&15)],
// Bmat[576][64] = [W_linear ; W_self].
__global__ void prep_cast_kernel(const float* __restrict__ Wlin,
                                 const float* __restrict__ Wself,
                                 const float* __restrict__ blin,
                                 const float* __restrict__ bself,
                                 const float4* __restrict__ x4,
                                 unsigned short* __restrict__ Bf2,
                                 float* __restrict__ bsum,
                                 us4* __restrict__ xb,
                                 int* __restrict__ bucket_cursor) {
  int gt = blockIdx.x * 256 + threadIdx.x;
  if (gt < NBUCK) bucket_cursor[gt] = 0;
  if (gt < 64) bsum[gt] = blin[gt] + bself[gt];
  if (blockIdx.x < CASTBLK) {
    int t = gt;
    if (t < NNODES * DIM / 4) {
      float4 v = x4[t];
      us4 o;
      o.x = f2bf(v.x); o.y = f2bf(v.y); o.z = f2bf(v.z); o.w = f2bf(v.w);
      xb[t] = o;
    }
  } else {
    int t = (blockIdx.x - CASTBLK) * 256 + threadIdx.x;
    if (t < 18 * 4 * 64 * 8) {
      int j  = t & 7;
      int l  = (t >> 3) & 63;
      int ct = (t >> 9) & 3;
      int ks = t >> 11;
      int k = ks * 32 + (l >> 4) * 8 + j;
      int c = ct * 16 + (l & 15);
      float v = (k < 512) ? Wlin[(size_t)k * 64 + c] : Wself[(size_t)(k - 512) * 64 + c];
      Bf2[t] = f2bf(v);
    }
  }
}

// K1: binned scatter. Record: x = src(16) | rel(3)<<16 | dst_low7(7)<<19, y = w bits.
__global__ __launch_bounds__(1024) void binscatter_kernel(
    const int4* __restrict__ src4, const int4* __restrict__ dst4,
    const int4* __restrict__ rel4, const float4* __restrict__ w4,
    int* __restrict__ bucket_cursor, uint2* __restrict__ staged, int E4) {
  __shared__ int lhist[NBUCK];
  __shared__ int lbase[NBUCK];
  int tid = threadIdx.x;
  if (tid < NBUCK) lhist[tid] = 0;
  __syncthreads();
  int t = blockIdx.x * 1024 + tid;
  bool valid = t < E4;
  int4 s = {0,0,0,0}, d = {0,0,0,0}, r = {0,0,0,0};
  float4 w = {0.f,0.f,0.f,0.f};
  if (valid) { s = src4[t]; d = dst4[t]; r = rel4[t]; w = w4[t]; }
  int b0=0,b1=0,b2=0,b3=0,p0=0,p1=0,p2=0,p3=0;
  if (valid) {
    b0 = d.x >> 7; p0 = atomicAdd(&lhist[b0], 1);
    b1 = d.y >> 7; p1 = atomicAdd(&lhist[b1], 1);
    b2 = d.z >> 7; p2 = atomicAdd(&lhist[b2], 1);
    b3 = d.w >> 7; p3 = atomicAdd(&lhist[b3], 1);
  }
  __syncthreads();
  if (tid < NBUCK && lhist[tid] > 0)
    lbase[tid] = atomicAdd(&bucket_cursor[tid], lhist[tid]);
  __syncthreads();
  if (valid) {
    int i0 = lbase[b0] + p0, i1 = lbase[b1] + p1, i2 = lbase[b2] + p2, i3 = lbase[b3] + p3;
    if (i0 < BCAP) staged[(size_t)b0 * BCAP + i0] =
      make_uint2((unsigned)s.x | ((unsigned)r.x << 16) | ((unsigned)(d.x & 127) << 19), __float_as_uint(w.x));
    if (i1 < BCAP) staged[(size_t)b1 * BCAP + i1] =
      make_uint2((unsigned)s.y | ((unsigned)r.y << 16) | ((unsigned)(d.y & 127) << 19), __float_as_uint(w.y));
    if (i2 < BCAP) staged[(size_t)b2 * BCAP + i2] =
      make_uint2((unsigned)s.z | ((unsigned)r.z << 16) | ((unsigned)(d.z & 127) << 19), __float_as_uint(w.z));
    if (i3 < BCAP) staged[(size_t)b3 * BCAP + i3] =
      make_uint2((unsigned)s.w | ((unsigned)r.w << 16) | ((unsigned)(d.w & 127) << 19), __float_as_uint(w.w));
  }
}

// K2: per-bucket: LDS-cache records, 1024-key hist+scan, write block offsets
// boff[] and meta = (src|rel|row4, w/deg) grouped by (node,rel).
__global__ __launch_bounds__(1024) void csrbuild_kernel(
    const int* __restrict__ bucket_cursor,
    const uint2* __restrict__ staged, uint2* __restrict__ meta, int* __restrict__ boff) {
  __shared__ uint2 cache[BCAP];                 // 23.0 KB
  __shared__ int   nhist[KEYS];
  __shared__ int   ncur[KEYS];
  __shared__ float degf[KEYS];
  __shared__ int   base_s;
  int b = blockIdx.x;
  int tid = threadIdx.x;
  int cnt  = bucket_cursor[b];
  if (cnt > BCAP) cnt = BCAP;
  if (tid >= 64 && tid < 128) {          // wave 1: bucket base = capped prefix sum
    int l = tid - 64;
    int ssum = 0;
    for (int i = l; i < b; i += 64) {
      int c = bucket_cursor[i];
      ssum += (c < BCAP) ? c : BCAP;
    }
    #pragma unroll
    for (int d = 1; d < 64; d <<= 1) ssum += __shfl_xor(ssum, d);
    if (l == 0) base_s = ssum;
  }
  if (tid < KEYS) { nhist[tid] = 0; degf[tid] = 0.f; }
  __syncthreads();
  const uint2* sb = staged + (size_t)b * BCAP;
  for (int i = tid; i < cnt; i += 1024) {
    uint2 rec = sb[i];
    cache[i] = rec;
    int key = (((rec.x >> 19) & 127) << 3) | ((rec.x >> 16) & 7);
    atomicAdd(&nhist[key], 1);
    atomicAdd(&degf[key], __uint_as_float(rec.y));
  }
  __syncthreads();
  if (tid < 64) {    // wave 0: scan 1024 keys (16 chunks of 64, serial carry)
    int carry = 0;
    #pragma unroll
    for (int s = 0; s < KEYS / 64; s++) {
      int v = nhist[s * 64 + tid];
      int inc = v;
      #pragma unroll
      for (int d = 1; d < 64; d <<= 1) {
        int tt = __shfl_up(inc, d);
        if (tid >= d) inc += tt;
      }
      ncur[s * 64 + tid] = carry + inc - v;
      carry += __shfl(inc, 63);
    }
  }
  __syncthreads();
  int base = base_s;
  if (tid < 8) {                          // block offsets (16-node granularity)
    int g = b * 8 + tid;
    if (g < NBLK) boff[g] = base + ncur[tid * 128];
  }
  if (b == 0 && tid == 0) boff[NBLK] = NEDGES;
  if (tid < KEYS) {
    float d = degf[tid];
    degf[tid] = (d != 0.f) ? (1.0f / d) : 0.f;
  }
  __syncthreads();
  for (int i = tid; i < cnt; i += 1024) {
    uint2 rec = cache[i];
    int key = (((rec.x >> 19) & 127) << 3) | ((rec.x >> 16) & 7);
    int pos = atomicAdd(&ncur[key], 1);
    float sc = __uint_as_float(rec.y) * degf[key];
    unsigned mx = (rec.x & 0x7FFFF) | (((rec.x >> 19) & 15) << 19);  // src|rel|row4
    meta[base + pos] = make_uint2(mx, __float_as_uint(sc));
  }
}

// K3: FUSED aggregate + output GEMM. Block = 16 nodes.
// Phase 1: flat per-wave edge loop (unroll x4, readlane->SGPR addressing),
// ds_add_f32 accumulation into At[16][577] f32 tile.
// Phase 2: LDS->bf16 pack (v_perm, round-half-up), 18 MFMA k-steps, +bias, relu.
__global__ __launch_bounds__(256) void fused_kernel(const int* __restrict__ boff,
                                                    const uint2* __restrict__ meta,
                                                    const unsigned short* __restrict__ xb,
                                                    const unsigned short* __restrict__ Bf2,
                                                    const float* __restrict__ bsum,
                                                    float* __restrict__ out) {
  __shared__ float At[16 * PITCHF];   // 36.1 KB
  int tid  = threadIdx.x;
  int wave = tid >> 6;
  int lane = tid & 63;
  int g = blockIdx.x;
  int nodeBase = g * 16;

  // init: zero update region (cols 0..511) and stage self columns (512..575)
  for (int i = tid; i < 16 * 512; i += 256) {
    int r = i >> 9, c = i & 511;
    At[r * PITCHF + c] = 0.f;
  }
  #pragma unroll
  for (int i = 0; i < 4; i++) {
    int row = wave * 4 + i;
    At[row * PITCHF + 512 + lane] = bf2f(xb[(size_t)(nodeBase + row) * 64 + lane]);
  }
  __syncthreads();

  int blo = boff[g];
  int bhi = boff[g + 1];

  for (int c0 = blo + wave * 64; c0 < bhi; c0 += 256) {
    int n = bhi - c0; if (n > 64) n = 64;
    uint2 mm = make_uint2(0u, 0u);
    if (lane < n) mm = meta[c0 + lane];          // coalesced 8B/lane

    #define EDGE_BODY(J) {                                                        \
      unsigned sx = (unsigned)__builtin_amdgcn_readlane((int)mm.x, (J));          \
      float ssc = __uint_as_float((unsigned)__builtin_amdgcn_readlane((int)mm.y, (J))); \
      int src = sx & 0xFFFF;                                                      \
      int rr  = (sx >> 16) & 7;                                                   \
      int row = (sx >> 19) & 15;                                                  \
      const unsigned short* p = xb + (size_t)src * 64;                            \
      float v = bf2f(p[lane]);                                                    \
      atomicAdd(&At[row * PITCHF + rr * 64 + lane], ssc * v);                     \
    }
    int j = 0;
    for (; j + 4 <= n; j += 4) {
      EDGE_BODY(j); EDGE_BODY(j + 1); EDGE_BODY(j + 2); EDGE_BODY(j + 3);
    }
    for (; j < n; j++) EDGE_BODY(j);
    #undef EDGE_BODY
  }
  __syncthreads();

  // Phase 2: MFMA; this wave's col tile = wave.
  int q = lane >> 4;
  int m = lane & 15;
  float4v acc4 = {0.f, 0.f, 0.f, 0.f};
  const short8* Bp = (const short8*)Bf2;
  #pragma unroll
  for (int ks = 0; ks < 18; ks++) {
    const float* ap = At + m * PITCHF + ks * 32 + q * 8;
    union { unsigned u[4]; short8 s8; } pk;
    #pragma unroll
    for (int h = 0; h < 4; h++) {
      unsigned u0 = __float_as_uint(ap[2 * h])     + 0x8000u;   // round-half-up
      unsigned u1 = __float_as_uint(ap[2 * h + 1]) + 0x8000u;
      pk.u[h] = __builtin_amdgcn_perm(u1, u0, 0x07060302);      // {hi16(u1),hi16(u0)}
    }
    short8 bfr = Bp[(ks * 4 + wave) * 64 + lane];
    acc4 = __builtin_amdgcn_mfma_f32_16x16x32_bf16(pk.s8, bfr, acc4, 0, 0, 0);
  }
  int c = wave * 16 + m;
  float bias = bsum[c];
  #pragma unroll
  for (int rr = 0; rr < 4; rr++) {
    out[(size_t)(nodeBase + q * 4 + rr) * 64 + c] = fmaxf(acc4[rr] + bias, 0.0f);
  }
}

extern "C" void kernel_launch(void* const* d_in, const int* in_sizes, int n_in,
                              void* d_out, int out_size, void* d_ws, size_t ws_size,
                              hipStream_t stream) {
  const float* x     = (const float*)d_in[0];
  const int*   esrc  = (const int*)d_in[1];
  const int*   edst  = (const int*)d_in[2];
  const int*   erel  = (const int*)d_in[3];
  const float* ew    = (const float*)d_in[4];
  const float* Wlin  = (const float*)d_in[5];
  const float* blin  = (const float*)d_in[6];
  const float* Wself = (const float*)d_in[7];
  const float* bself = (const float*)d_in[8];
  float* out = (float*)d_out;

  char* ws = (char*)d_ws;
  size_t off = 0;
  auto alloc = [&](size_t bytes) -> void* {
    void* p = ws + off;
    off += (bytes + 255) & ~(size_t)255;
    return p;
  };
  int*            bucket_cursor = (int*)alloc((size_t)NBUCK * sizeof(int));           // zeroed in prep_cast
  int*            boff    = (int*)alloc((size_t)(NBLK + 8) * sizeof(int));
  uint2*          staged  = (uint2*)alloc((size_t)NBUCK * BCAP * sizeof(uint2));      // 9.2 MB
  uint2*          meta    = (uint2*)alloc((size_t)NEDGES * sizeof(uint2));            // 8 MB
  unsigned short* Bf2     = (unsigned short*)alloc((size_t)18 * 4 * 64 * 8 * sizeof(unsigned short));
  float*          bsum    = (float*)alloc(64 * sizeof(float));
  unsigned short* xb      = (unsigned short*)alloc((size_t)NNODES * DIM * sizeof(unsigned short));  // 6.4 MB

  const int E4 = NEDGES / 4;
  prep_cast_kernel<<<CASTBLK + PREPBLK, 256, 0, stream>>>(Wlin, Wself, blin, bself,
                                                          (const float4*)x, Bf2, bsum,
                                                          (us4*)xb, bucket_cursor);
  binscatter_kernel<<<(E4 + 1023) / 1024, 1024, 0, stream>>>((const int4*)esrc, (const int4*)edst,
                                                             (const int4*)erel, (const float4*)ew,
                                                             bucket_cursor, staged, E4);
  csrbuild_kernel<<<NBUCK, 1024, 0, stream>>>(bucket_cursor, staged, meta, boff);
  fused_kernel<<<NBLK, 256, 0, stream>>>(boff, meta, xb, Bf2, bsum, out);
}

// Round 8
// 168.892 us; speedup vs baseline: 2.8176x; 2.8176x over previous
//
#include <hip/hip_runtime.h>
#include <stdint.h>

// Problem constants (from reference)
#define NNODES 50000
#define NEDGES 1000000
#define DIM    64
#define NREL   8
#define NBUCK  391          // ceil(50000/128); bucket = dst >> 7 (128-node range)
#define BCAP   2944         // per-bucket staging capacity (expected ~2558, +7.6 sigma)
#define KEYS   1024         // 128 nodes x 8 rels per bucket
#define NBLK   3125         // 50000 / 16 output blocks
#define APITCH 584          // LDS bf16 tile pitch (576 + 8)

typedef __attribute__((ext_vector_type(8))) short short8;
typedef __attribute__((ext_vector_type(4))) float float4v;
typedef __attribute__((ext_vector_type(4))) unsigned short us4;

__device__ __forceinline__ float bf2f(unsigned short u) {
  return __uint_as_float(((unsigned int)u) << 16);
}
__device__ __forceinline__ unsigned short f2bf(float f) {
  unsigned int u = __float_as_uint(f);
  unsigned int r = (u + 0x7FFF + ((u >> 16) & 1)) >> 16;   // round-nearest-even
  return (unsigned short)r;
}

#define CASTBLK ((NNODES * DIM / 4 + 255) / 256)
#define PREPBLK ((18 * 4 * 64 * 8 + 255) / 256)

// K0: fused prep (B fragments + bias) and x f32->bf16 cast; zero bucket_cursor.
// Bf2[((ks*4+ct)*64 + l)*8 + j] = Bmat[ks*32 + (l>>4)*8 + j][ct*16 + (l&15)],
// Bmat[576][64] = [W_linear ; W_self].
__global__ void prep_cast_kernel(const float* __restrict__ Wlin,
                                 const float* __restrict__ Wself,
                                 const float* __restrict__ blin,
                                 const float* __restrict__ bself,
                                 const float4* __restrict__ x4,
                                 unsigned short* __restrict__ Bf2,
                                 float* __restrict__ bsum,
                                 us4* __restrict__ xb,
                                 int* __restrict__ bucket_cursor) {
  int gt = blockIdx.x * 256 + threadIdx.x;
  if (gt < NBUCK) bucket_cursor[gt] = 0;
  if (gt < 64) bsum[gt] = blin[gt] + bself[gt];
  if (blockIdx.x < CASTBLK) {
    int t = gt;
    if (t < NNODES * DIM / 4) {
      float4 v = x4[t];
      us4 o;
      o.x = f2bf(v.x); o.y = f2bf(v.y); o.z = f2bf(v.z); o.w = f2bf(v.w);
      xb[t] = o;
    }
  } else {
    int t = (blockIdx.x - CASTBLK) * 256 + threadIdx.x;
    if (t < 18 * 4 * 64 * 8) {
      int j  = t & 7;
      int l  = (t >> 3) & 63;
      int ct = (t >> 9) & 3;
      int ks = t >> 11;
      int k = ks * 32 + (l >> 4) * 8 + j;
      int c = ct * 16 + (l & 15);
      float v = (k < 512) ? Wlin[(size_t)k * 64 + c] : Wself[(size_t)(k - 512) * 64 + c];
      Bf2[t] = f2bf(v);
    }
  }
}

// K1: binned scatter. Record: x = src(16) | rel(3)<<16 | dst_low7(7)<<19, y = w bits.
__global__ __launch_bounds__(1024) void binscatter_kernel(
    const int4* __restrict__ src4, const int4* __restrict__ dst4,
    const int4* __restrict__ rel4, const float4* __restrict__ w4,
    int* __restrict__ bucket_cursor, uint2* __restrict__ staged, int E4) {
  __shared__ int lhist[NBUCK];
  __shared__ int lbase[NBUCK];
  int tid = threadIdx.x;
  if (tid < NBUCK) lhist[tid] = 0;
  __syncthreads();
  int t = blockIdx.x * 1024 + tid;
  bool valid = t < E4;
  int4 s = {0,0,0,0}, d = {0,0,0,0}, r = {0,0,0,0};
  float4 w = {0.f,0.f,0.f,0.f};
  if (valid) { s = src4[t]; d = dst4[t]; r = rel4[t]; w = w4[t]; }
  int b0=0,b1=0,b2=0,b3=0,p0=0,p1=0,p2=0,p3=0;
  if (valid) {
    b0 = d.x >> 7; p0 = atomicAdd(&lhist[b0], 1);
    b1 = d.y >> 7; p1 = atomicAdd(&lhist[b1], 1);
    b2 = d.z >> 7; p2 = atomicAdd(&lhist[b2], 1);
    b3 = d.w >> 7; p3 = atomicAdd(&lhist[b3], 1);
  }
  __syncthreads();
  if (tid < NBUCK && lhist[tid] > 0)
    lbase[tid] = atomicAdd(&bucket_cursor[tid], lhist[tid]);
  __syncthreads();
  if (valid) {
    int i0 = lbase[b0] + p0, i1 = lbase[b1] + p1, i2 = lbase[b2] + p2, i3 = lbase[b3] + p3;
    if (i0 < BCAP) staged[(size_t)b0 * BCAP + i0] =
      make_uint2((unsigned)s.x | ((unsigned)r.x << 16) | ((unsigned)(d.x & 127) << 19), __float_as_uint(w.x));
    if (i1 < BCAP) staged[(size_t)b1 * BCAP + i1] =
      make_uint2((unsigned)s.y | ((unsigned)r.y << 16) | ((unsigned)(d.y & 127) << 19), __float_as_uint(w.y));
    if (i2 < BCAP) staged[(size_t)b2 * BCAP + i2] =
      make_uint2((unsigned)s.z | ((unsigned)r.z << 16) | ((unsigned)(d.z & 127) << 19), __float_as_uint(w.z));
    if (i3 < BCAP) staged[(size_t)b3 * BCAP + i3] =
      make_uint2((unsigned)s.w | ((unsigned)r.w << 16) | ((unsigned)(d.w & 127) << 19), __float_as_uint(w.w));
  }
}

// K2: per-bucket: LDS-cache records, 1024-key hist+scan, write per-(node,rel)
// segment offsets roff[] and meta = (src*128 byte-offset, w/deg) grouped by (node,rel).
__global__ __launch_bounds__(1024) void csrbuild_kernel(
    const int* __restrict__ bucket_cursor,
    const uint2* __restrict__ staged, uint2* __restrict__ meta, int* __restrict__ roff) {
  __shared__ uint2 cache[BCAP];                 // 23.0 KB
  __shared__ int   nhist[KEYS];
  __shared__ int   ncur[KEYS];
  __shared__ float degf[KEYS];
  __shared__ int   base_s;
  int b = blockIdx.x;
  int tid = threadIdx.x;
  int cnt  = bucket_cursor[b];
  if (cnt > BCAP) cnt = BCAP;
  if (tid >= 64 && tid < 128) {          // wave 1: bucket base = capped prefix sum
    int l = tid - 64;
    int ssum = 0;
    for (int i = l; i < b; i += 64) {
      int c = bucket_cursor[i];
      ssum += (c < BCAP) ? c : BCAP;
    }
    #pragma unroll
    for (int d = 1; d < 64; d <<= 1) ssum += __shfl_xor(ssum, d);
    if (l == 0) base_s = ssum;
  }
  if (tid < KEYS) { nhist[tid] = 0; degf[tid] = 0.f; }
  __syncthreads();
  const uint2* sb = staged + (size_t)b * BCAP;
  for (int i = tid; i < cnt; i += 1024) {
    uint2 rec = sb[i];
    cache[i] = rec;
    int key = (((rec.x >> 19) & 127) << 3) | ((rec.x >> 16) & 7);
    atomicAdd(&nhist[key], 1);
    atomicAdd(&degf[key], __uint_as_float(rec.y));
  }
  __syncthreads();
  if (tid < 64) {    // wave 0: scan 1024 keys (16 chunks of 64, serial carry)
    int carry = 0;
    #pragma unroll
    for (int s = 0; s < KEYS / 64; s++) {
      int v = nhist[s * 64 + tid];
      int inc = v;
      #pragma unroll
      for (int d = 1; d < 64; d <<= 1) {
        int tt = __shfl_up(inc, d);
        if (tid >= d) inc += tt;
      }
      ncur[s * 64 + tid] = carry + inc - v;
      carry += __shfl(inc, 63);
    }
  }
  __syncthreads();
  int base = base_s;
  int gk0 = b * KEYS;
  int nk = NNODES * NREL - gk0; if (nk > KEYS) nk = KEYS;
  if (tid < nk) roff[gk0 + tid] = base + ncur[tid];
  if (b == 0 && tid == 0) roff[NNODES * NREL] = NEDGES;
  if (tid < KEYS) {
    float d = degf[tid];
    degf[tid] = (d != 0.f) ? (1.0f / d) : 0.f;
  }
  __syncthreads();
  for (int i = tid; i < cnt; i += 1024) {
    uint2 rec = cache[i];
    int key = (((rec.x >> 19) & 127) << 3) | ((rec.x >> 16) & 7);
    int pos = atomicAdd(&ncur[key], 1);
    float sc = __uint_as_float(rec.y) * degf[key];
    meta[base + pos] = make_uint2((rec.x & 0xFFFF) << 7, __float_as_uint(sc));  // src*128 bytes
  }
}

// K3: FUSED aggregate + output GEMM. Block = 16 nodes (4 waves x 4 nodes serial).
// Edge engine: per (node,rel) segment, scalar s_load of meta (uniform index) ->
// SGPR-base gather global_load_ushort (saddr + 2*lane) -> v_lshl + v_fmac(SGPR scale).
// 2 VALU + 1 VMEM per edge, no bpermute, no LDS in the edge loop.
__global__ __launch_bounds__(256) void fused_kernel(const int* __restrict__ roff,
                                                    const uint2* __restrict__ meta,
                                                    const unsigned short* __restrict__ xb,
                                                    const unsigned short* __restrict__ Bf2,
                                                    const float* __restrict__ bsum,
                                                    float* __restrict__ out) {
  __shared__ unsigned short At[16 * APITCH];   // 18.25 KB
  int tid  = threadIdx.x;
  int wave = tid >> 6;
  int lane = tid & 63;
  int nodeBase = blockIdx.x * 16;
  const char* xbb = (const char*)xb;
  int lane2 = lane * 2;

  #pragma unroll
  for (int i = 0; i < 4; i++) {
    int row  = wave * 4 + i;
    int node = nodeBase + row;
    int bnd = 0;
    if (lane < 9) bnd = roff[node * NREL + lane];

    int eb[9];
    #pragma unroll
    for (int k = 0; k < 9; k++) eb[k] = __builtin_amdgcn_readlane(bnd, k);  // SGPR bounds

    float acc[8];
    #pragma unroll
    for (int r = 0; r < 8; r++) acc[r] = 0.f;

    #pragma unroll
    for (int r = 0; r < 8; r++) {
      int e  = eb[r];
      int e1 = eb[r + 1];
      for (; e + 2 <= e1; e += 2) {
        uint2 m0 = meta[e];          // uniform -> s_load_dwordx2
        uint2 m1 = meta[e + 1];
        float v0 = bf2f(*(const unsigned short*)(xbb + m0.x + lane2));
        float v1 = bf2f(*(const unsigned short*)(xbb + m1.x + lane2));
        acc[r] += __uint_as_float(m0.y) * v0;
        acc[r] += __uint_as_float(m1.y) * v1;
      }
      if (e < e1) {
        uint2 m0 = meta[e];
        acc[r] += __uint_as_float(m0.y) * bf2f(*(const unsigned short*)(xbb + m0.x + lane2));
      }
    }
    unsigned short* ar = At + row * APITCH;
    #pragma unroll
    for (int r = 0; r < 8; r++) ar[r * 64 + lane] = f2bf(acc[r]);
    ar[512 + lane] = xb[(size_t)node * 64 + lane];   // self-loop block
  }
  __syncthreads();

  // Phase 2: MFMA; this wave's col tile = wave.
  int q = lane >> 4;
  int m = lane & 15;
  float4v acc4 = {0.f, 0.f, 0.f, 0.f};
  const short8* Bp = (const short8*)Bf2;
  #pragma unroll
  for (int ks = 0; ks < 18; ks++) {
    short8 a = *(const short8*)(At + m * APITCH + ks * 32 + q * 8);
    short8 bfr = Bp[(ks * 4 + wave) * 64 + lane];
    acc4 = __builtin_amdgcn_mfma_f32_16x16x32_bf16(a, bfr, acc4, 0, 0, 0);
  }
  int c = wave * 16 + m;
  float bias = bsum[c];
  #pragma unroll
  for (int rr = 0; rr < 4; rr++) {
    out[(size_t)(nodeBase + q * 4 + rr) * 64 + c] = fmaxf(acc4[rr] + bias, 0.0f);
  }
}

extern "C" void kernel_launch(void* const* d_in, const int* in_sizes, int n_in,
                              void* d_out, int out_size, void* d_ws, size_t ws_size,
                              hipStream_t stream) {
  const float* x     = (const float*)d_in[0];
  const int*   esrc  = (const int*)d_in[1];
  const int*   edst  = (const int*)d_in[2];
  const int*   erel  = (const int*)d_in[3];
  const float* ew    = (const float*)d_in[4];
  const float* Wlin  = (const float*)d_in[5];
  const float* blin  = (const float*)d_in[6];
  const float* Wself = (const float*)d_in[7];
  const float* bself = (const float*)d_in[8];
  float* out = (float*)d_out;

  char* ws = (char*)d_ws;
  size_t off = 0;
  auto alloc = [&](size_t bytes) -> void* {
    void* p = ws + off;
    off += (bytes + 255) & ~(size_t)255;
    return p;
  };
  int*            bucket_cursor = (int*)alloc((size_t)NBUCK * sizeof(int));           // zeroed in prep_cast
  int*            roff    = (int*)alloc((size_t)(NNODES * NREL + 8) * sizeof(int));   // 1.6 MB
  uint2*          staged  = (uint2*)alloc((size_t)NBUCK * BCAP * sizeof(uint2));      // 9.2 MB
  uint2*          meta    = (uint2*)alloc((size_t)NEDGES * sizeof(uint2));            // 8 MB
  unsigned short* Bf2     = (unsigned short*)alloc((size_t)18 * 4 * 64 * 8 * sizeof(unsigned short));
  float*          bsum    = (float*)alloc(64 * sizeof(float));
  unsigned short* xb      = (unsigned short*)alloc((size_t)NNODES * DIM * sizeof(unsigned short));  // 6.4 MB

  const int E4 = NEDGES / 4;
  prep_cast_kernel<<<CASTBLK + PREPBLK, 256, 0, stream>>>(Wlin, Wself, blin, bself,
                                                          (const float4*)x, Bf2, bsum,
                                                          (us4*)xb, bucket_cursor);
  binscatter_kernel<<<(E4 + 1023) / 1024, 1024, 0, stream>>>((const int4*)esrc, (const int4*)edst,
                                                             (const int4*)erel, (const float4*)ew,
                                                             bucket_cursor, staged, E4);
  csrbuild_kernel<<<NBUCK, 1024, 0, stream>>>(bucket_cursor, staged, meta, roff);
  fused_kernel<<<NBLK, 256, 0, stream>>>(roff, meta, xb, Bf2, bsum, out);
}